// Round 2
// baseline (12055.983 us; speedup 1.0000x reference)
//
#include <hip/hip_runtime.h>
#include <math.h>

// ---------------- degree / normalization ----------------

__global__ __launch_bounds__(256) void k_init_deg(int* deg, int n) {
    int i = blockIdx.x * blockDim.x + threadIdx.x;
    if (i < n) deg[i] = 1;  // self-loop
}

__global__ __launch_bounds__(256) void k_count_deg(const int* __restrict__ dst, int E, int* deg) {
    int i = blockIdx.x * blockDim.x + threadIdx.x;
    if (i < E) atomicAdd(&deg[dst[i]], 1);
}

__global__ __launch_bounds__(256) void k_dis(const int* __restrict__ deg, float* __restrict__ dis, int n) {
    int i = blockIdx.x * blockDim.x + threadIdx.x;
    if (i < n) dis[i] = rsqrtf((float)deg[i]);
}

// ---------------- tiled fp32 GEMM: C[M,N] = A[M,K] @ B[K,N] (optional relu on A) ----------------
// BM=64, BN=64, BK=16, 256 threads, 4x4 per thread.

template <bool RELU>
__global__ __launch_bounds__(256) void k_gemm(const float* __restrict__ A,
                                              const float* __restrict__ B,
                                              float* __restrict__ C,
                                              int M, int N, int K) {
    const int BM = 64, BN = 64, BK = 16;
    __shared__ float As[BK][BM + 1];   // transposed, padded (scalar writes)
    __shared__ float Bs[BK][BN];       // natural, 16B-aligned rows for b128 ops

    const int t  = threadIdx.x;
    const int tx = t % 16, ty = t / 16;
    const int m0 = blockIdx.x * BM, n0 = blockIdx.y * BN;

    float acc[4][4] = {};

    for (int k0 = 0; k0 < K; k0 += BK) {
        // A tile: 64 rows x 16 cols; thread -> (row = t/4, 4 consecutive k)
        {
            int row = t >> 2;
            int kg  = (t & 3) * 4;
            int gm  = m0 + row;
            float4 v = make_float4(0.f, 0.f, 0.f, 0.f);
            if (gm < M) v = *reinterpret_cast<const float4*>(&A[(size_t)gm * K + k0 + kg]);
            if (RELU) {
                v.x = fmaxf(v.x, 0.f); v.y = fmaxf(v.y, 0.f);
                v.z = fmaxf(v.z, 0.f); v.w = fmaxf(v.w, 0.f);
            }
            As[kg + 0][row] = v.x;
            As[kg + 1][row] = v.y;
            As[kg + 2][row] = v.z;
            As[kg + 3][row] = v.w;
        }
        // B tile: 16 rows x 64 cols; thread -> (row = t/16, 4 consecutive n)
        {
            int row = t >> 4;
            int ng  = (t & 15) * 4;
            float4 v = *reinterpret_cast<const float4*>(&B[(size_t)(k0 + row) * N + n0 + ng]);
            *reinterpret_cast<float4*>(&Bs[row][ng]) = v;
        }
        __syncthreads();

        #pragma unroll
        for (int k = 0; k < BK; ++k) {
            float a[4], b[4];
            #pragma unroll
            for (int i = 0; i < 4; ++i) a[i] = As[k][ty * 4 + i];
            float4 bv = *reinterpret_cast<const float4*>(&Bs[k][tx * 4]);
            b[0] = bv.x; b[1] = bv.y; b[2] = bv.z; b[3] = bv.w;
            #pragma unroll
            for (int i = 0; i < 4; ++i)
                #pragma unroll
                for (int j = 0; j < 4; ++j)
                    acc[i][j] = fmaf(a[i], b[j], acc[i][j]);
        }
        __syncthreads();
    }

    #pragma unroll
    for (int i = 0; i < 4; ++i) {
        int gm = m0 + ty * 4 + i;
        if (gm < M) {
            float4 o = make_float4(acc[i][0], acc[i][1], acc[i][2], acc[i][3]);
            *reinterpret_cast<float4*>(&C[(size_t)gm * N + n0 + tx * 4]) = o;
        }
    }
}

// ---------------- out init: out[i][f] = bias[f] + h[i][f] * dis[i]^2 (self-loop) ----------------
// F4 = feats/4

__global__ __launch_bounds__(256) void k_init_out(const float* __restrict__ h,
                                                  const float* __restrict__ dis,
                                                  const float* __restrict__ bias,
                                                  float* __restrict__ out,
                                                  int n, int F4) {
    size_t idx = (size_t)blockIdx.x * blockDim.x + threadIdx.x;
    size_t total = (size_t)n * F4;
    if (idx >= total) return;
    int i = (int)(idx / F4);
    int c = (int)(idx % F4);
    float s = dis[i];
    s = s * s;
    float4 hv = reinterpret_cast<const float4*>(h)[idx];
    float4 bv = reinterpret_cast<const float4*>(bias)[c];
    float4 o;
    o.x = fmaf(hv.x, s, bv.x);
    o.y = fmaf(hv.y, s, bv.y);
    o.z = fmaf(hv.z, s, bv.z);
    o.w = fmaf(hv.w, s, bv.w);
    reinterpret_cast<float4*>(out)[idx] = o;
}

// ---------------- edge scatter, 256 feats: one wave per edge ----------------

__global__ __launch_bounds__(256) void k_scatter256(const int* __restrict__ srcs,
                                                    const int* __restrict__ dsts, int E,
                                                    const float* __restrict__ dis,
                                                    const float* __restrict__ h,
                                                    float* __restrict__ out) {
    int wave  = (int)((blockIdx.x * (size_t)blockDim.x + threadIdx.x) >> 6);
    int lane  = threadIdx.x & 63;
    int nwave = (int)((gridDim.x * (size_t)blockDim.x) >> 6);
    for (int e = wave; e < E; e += nwave) {
        int s = srcs[e], d = dsts[e];
        float nrm = dis[s] * dis[d];
        float4 v = reinterpret_cast<const float4*>(h + (size_t)s * 256)[lane];
        float* op = out + (size_t)d * 256 + lane * 4;
        atomicAdd(op + 0, v.x * nrm);
        atomicAdd(op + 1, v.y * nrm);
        atomicAdd(op + 2, v.z * nrm);
        atomicAdd(op + 3, v.w * nrm);
    }
}

// ---------------- edge scatter, 64 feats: one wave per edge, one float per lane ----------------

__global__ __launch_bounds__(256) void k_scatter64(const int* __restrict__ srcs,
                                                   const int* __restrict__ dsts, int E,
                                                   const float* __restrict__ dis,
                                                   const float* __restrict__ h,
                                                   float* __restrict__ out) {
    int wave  = (int)((blockIdx.x * (size_t)blockDim.x + threadIdx.x) >> 6);
    int lane  = threadIdx.x & 63;
    int nwave = (int)((gridDim.x * (size_t)blockDim.x) >> 6);
    for (int e = wave; e < E; e += nwave) {
        int s = srcs[e], d = dsts[e];
        float nrm = dis[s] * dis[d];
        float v = h[(size_t)s * 64 + lane];
        atomicAdd(out + (size_t)d * 64 + lane, v * nrm);
    }
}

// ---------------- log_softmax over rows of 64, in place ----------------

__global__ __launch_bounds__(256) void k_logsoftmax64(float* __restrict__ out, int n) {
    int wave = (int)((blockIdx.x * (size_t)blockDim.x + threadIdx.x) >> 6);
    int lane = threadIdx.x & 63;
    if (wave >= n) return;
    float v = out[(size_t)wave * 64 + lane];
    float m = v;
    #pragma unroll
    for (int o = 32; o > 0; o >>= 1) m = fmaxf(m, __shfl_xor(m, o));
    float ex = __expf(v - m);
    float ssum = ex;
    #pragma unroll
    for (int o = 32; o > 0; o >>= 1) ssum += __shfl_xor(ssum, o);
    out[(size_t)wave * 64 + lane] = v - m - logf(ssum);
}

// ---------------- launch ----------------

extern "C" void kernel_launch(void* const* d_in, const int* in_sizes, int n_in,
                              void* d_out, int out_size, void* d_ws, size_t ws_size,
                              hipStream_t stream) {
    const float* x  = (const float*)d_in[0];
    const int*   ei = (const int*)d_in[1];
    const float* W1 = (const float*)d_in[2];
    const float* b1 = (const float*)d_in[3];
    const float* W2 = (const float*)d_in[4];
    const float* b2 = (const float*)d_in[5];
    float* out = (float*)d_out;

    const int n = in_sizes[0] / 512;     // 100000
    const int E = in_sizes[1] / 2;       // 3200000
    const int* src = ei;
    const int* dst = ei + E;

    // workspace layout (bytes)
    char* ws = (char*)d_ws;
    int*   deg  = (int*)(ws + 0);                        // 400,000 B
    float* dis  = (float*)(ws + 400000);                 // 400,000 B
    float* h1   = (float*)(ws + 800000);                 // 102,400,000 B  (also reused as h2)
    float* out1 = (float*)(ws + 800000 + 102400000);     // 102,400,000 B
    float* h2   = h1;                                    // reuse after out1 done with h1

    const int TB = 256;

    // 1. degrees (with self-loop) and deg^-1/2
    k_init_deg<<<(n + TB - 1) / TB, TB, 0, stream>>>(deg, n);
    k_count_deg<<<(E + TB - 1) / TB, TB, 0, stream>>>(dst, E, deg);
    k_dis<<<(n + TB - 1) / TB, TB, 0, stream>>>(deg, dis, n);

    // 2. h1 = x @ W1   [n,512]@[512,256]
    {
        dim3 grid((n + 63) / 64, 256 / 64);
        k_gemm<false><<<grid, TB, 0, stream>>>(x, W1, h1, n, 256, 512);
    }

    // 3. out1 = b1 + selfloop + scatter
    {
        size_t total4 = (size_t)n * 64;
        k_init_out<<<(unsigned)((total4 + TB - 1) / TB), TB, 0, stream>>>(h1, dis, b1, out1, n, 64);
        k_scatter256<<<2048, TB, 0, stream>>>(src, dst, E, dis, h1, out1);
    }

    // 4. h2 = relu(out1) @ W2   [n,256]@[256,64]
    {
        dim3 grid((n + 63) / 64, 64 / 64);
        k_gemm<true><<<grid, TB, 0, stream>>>(out1, W2, h2, n, 64, 256);
    }

    // 5. out = b2 + selfloop + scatter  (accumulate directly in d_out)
    {
        size_t total4 = (size_t)n * 16;
        k_init_out<<<(unsigned)((total4 + TB - 1) / TB), TB, 0, stream>>>(h2, dis, b2, out, n, 16);
        k_scatter64<<<2048, TB, 0, stream>>>(src, dst, E, dis, h2, out);
    }

    // 6. log_softmax rows of 64, in place: one wave per row -> n waves -> n*64 threads
    k_logsoftmax64<<<(n * 64 + TB - 1) / TB, TB, 0, stream>>>(out, n);
}

// Round 3
// 1532.262 us; speedup vs baseline: 7.8681x; 7.8681x over previous
//
#include <hip/hip_runtime.h>
#include <math.h>

#define TB 256

// ---------------- degree / normalization ----------------

__global__ __launch_bounds__(256) void k_init_deg(int* deg, int* cursor, int n) {
    int i = blockIdx.x * blockDim.x + threadIdx.x;
    if (i < n) { deg[i] = 1; cursor[i] = 0; }  // self-loop counts once
}

__global__ __launch_bounds__(256) void k_count_deg(const int* __restrict__ dst, int E, int* deg) {
    int i = blockIdx.x * blockDim.x + threadIdx.x;
    if (i < E) atomicAdd(&deg[dst[i]], 1);
}

__global__ __launch_bounds__(256) void k_dis(const int* __restrict__ deg, float* __restrict__ dis, int n) {
    int i = blockIdx.x * blockDim.x + threadIdx.x;
    if (i < n) dis[i] = rsqrtf((float)deg[i]);
}

// ---------------- exclusive scan of in-edge counts (deg-1), single block ----------------

__global__ __launch_bounds__(1024) void k_scan(const int* __restrict__ deg, int* __restrict__ offsets, int n) {
    __shared__ int sums[1024];
    int t = threadIdx.x;
    int C = (n + 1023) / 1024;
    int lo = t * C, hi = min(n, lo + C);
    int s = 0;
    for (int i = lo; i < hi; ++i) s += deg[i] - 1;
    sums[t] = s;
    __syncthreads();
    for (int off = 1; off < 1024; off <<= 1) {
        int v = (t >= off) ? sums[t - off] : 0;
        __syncthreads();
        sums[t] += v;
        __syncthreads();
    }
    int base = (t == 0) ? 0 : sums[t - 1];
    for (int i = lo; i < hi; ++i) { offsets[i] = base; base += deg[i] - 1; }
}

// ---------------- CSR fill (by dst) ----------------

__global__ __launch_bounds__(256) void k_fill(const int* __restrict__ src, const int* __restrict__ dst, int E,
                                              const int* __restrict__ offsets, int* cursor,
                                              int* __restrict__ csr_src) {
    int e = blockIdx.x * blockDim.x + threadIdx.x;
    if (e >= E) return;
    int d = dst[e];
    int pos = offsets[d] + atomicAdd(&cursor[d], 1);
    csr_src[pos] = src[e];
}

// ---------------- tiled fp32 GEMM: C[M,N] = A[M,K] @ B[K,N] (optional relu on A) ----------------

template <bool RELU>
__global__ __launch_bounds__(256) void k_gemm(const float* __restrict__ A,
                                              const float* __restrict__ B,
                                              float* __restrict__ C,
                                              int M, int N, int K) {
    const int BM = 64, BN = 64, BK = 16;
    __shared__ float As[BK][BM + 1];
    __shared__ float Bs[BK][BN];

    const int t  = threadIdx.x;
    const int tx = t % 16, ty = t / 16;
    const int m0 = blockIdx.x * BM, n0 = blockIdx.y * BN;

    float acc[4][4] = {};

    for (int k0 = 0; k0 < K; k0 += BK) {
        {
            int row = t >> 2;
            int kg  = (t & 3) * 4;
            int gm  = m0 + row;
            float4 v = make_float4(0.f, 0.f, 0.f, 0.f);
            if (gm < M) v = *reinterpret_cast<const float4*>(&A[(size_t)gm * K + k0 + kg]);
            if (RELU) {
                v.x = fmaxf(v.x, 0.f); v.y = fmaxf(v.y, 0.f);
                v.z = fmaxf(v.z, 0.f); v.w = fmaxf(v.w, 0.f);
            }
            As[kg + 0][row] = v.x;
            As[kg + 1][row] = v.y;
            As[kg + 2][row] = v.z;
            As[kg + 3][row] = v.w;
        }
        {
            int row = t >> 4;
            int ng  = (t & 15) * 4;
            float4 v = *reinterpret_cast<const float4*>(&B[(size_t)(k0 + row) * N + n0 + ng]);
            *reinterpret_cast<float4*>(&Bs[row][ng]) = v;
        }
        __syncthreads();

        #pragma unroll
        for (int k = 0; k < BK; ++k) {
            float a[4], b[4];
            #pragma unroll
            for (int i = 0; i < 4; ++i) a[i] = As[k][ty * 4 + i];
            float4 bv = *reinterpret_cast<const float4*>(&Bs[k][tx * 4]);
            b[0] = bv.x; b[1] = bv.y; b[2] = bv.z; b[3] = bv.w;
            #pragma unroll
            for (int i = 0; i < 4; ++i)
                #pragma unroll
                for (int j = 0; j < 4; ++j)
                    acc[i][j] = fmaf(a[i], b[j], acc[i][j]);
        }
        __syncthreads();
    }

    #pragma unroll
    for (int i = 0; i < 4; ++i) {
        int gm = m0 + ty * 4 + i;
        if (gm < M) {
            float4 o = make_float4(acc[i][0], acc[i][1], acc[i][2], acc[i][3]);
            *reinterpret_cast<float4*>(&C[(size_t)gm * N + n0 + tx * 4]) = o;
        }
    }
}

// ---------------- gather-side aggregation: one wave per dst node ----------------
// out[i] = bias + h[i]*dis[i]^2 + sum_{s in N(i)} h[s]*dis[s]*dis[i]

template <int F>
__global__ __launch_bounds__(256) void k_aggregate(const float* __restrict__ h,
                                                   const int* __restrict__ csr_src,
                                                   const int* __restrict__ offsets,
                                                   const int* __restrict__ deg,
                                                   const float* __restrict__ dis,
                                                   const float* __restrict__ bias,
                                                   float* __restrict__ out, int n) {
    int wave = (int)((blockIdx.x * (size_t)blockDim.x + threadIdx.x) >> 6);
    int lane = threadIdx.x & 63;
    if (wave >= n) return;
    const int i = wave;
    const float di = dis[i];
    const int beg = offsets[i];
    const int cnt = deg[i] - 1;
    const int end = beg + cnt;

    if (F == 256) {
        float4 bv = reinterpret_cast<const float4*>(bias)[lane];
        float4 hv = reinterpret_cast<const float4*>(h + (size_t)i * 256)[lane];
        float sl = di * di;
        float4 acc;
        acc.x = fmaf(hv.x, sl, bv.x);
        acc.y = fmaf(hv.y, sl, bv.y);
        acc.z = fmaf(hv.z, sl, bv.z);
        acc.w = fmaf(hv.w, sl, bv.w);
        for (int base = beg; base < end; base += 64) {
            int m = end - base; if (m > 64) m = 64;
            int   msrc = (lane < m) ? csr_src[base + lane] : 0;
            float mnrm = (lane < m) ? dis[msrc] : 0.f;
            for (int k = 0; k < m; ++k) {
                int   s   = __shfl(msrc, k);
                float nrm = __shfl(mnrm, k) * di;
                float4 v = reinterpret_cast<const float4*>(h + (size_t)s * 256)[lane];
                acc.x = fmaf(v.x, nrm, acc.x);
                acc.y = fmaf(v.y, nrm, acc.y);
                acc.z = fmaf(v.z, nrm, acc.z);
                acc.w = fmaf(v.w, nrm, acc.w);
            }
        }
        reinterpret_cast<float4*>(out + (size_t)i * 256)[lane] = acc;
    } else {  // F == 64
        float acc = fmaf(h[(size_t)i * 64 + lane], di * di, bias[lane]);
        for (int base = beg; base < end; base += 64) {
            int m = end - base; if (m > 64) m = 64;
            int   msrc = (lane < m) ? csr_src[base + lane] : 0;
            float mnrm = (lane < m) ? dis[msrc] : 0.f;
            for (int k = 0; k < m; ++k) {
                int   s   = __shfl(msrc, k);
                float nrm = __shfl(mnrm, k) * di;
                acc = fmaf(h[(size_t)s * 64 + lane], nrm, acc);
            }
        }
        out[(size_t)i * 64 + lane] = acc;
    }
}

// ---------------- log_softmax over rows of 64, in place ----------------

__global__ __launch_bounds__(256) void k_logsoftmax64(float* __restrict__ out, int n) {
    int wave = (int)((blockIdx.x * (size_t)blockDim.x + threadIdx.x) >> 6);
    int lane = threadIdx.x & 63;
    if (wave >= n) return;
    float v = out[(size_t)wave * 64 + lane];
    float m = v;
    #pragma unroll
    for (int o = 32; o > 0; o >>= 1) m = fmaxf(m, __shfl_xor(m, o));
    float ex = __expf(v - m);
    float ssum = ex;
    #pragma unroll
    for (int o = 32; o > 0; o >>= 1) ssum += __shfl_xor(ssum, o);
    out[(size_t)wave * 64 + lane] = v - m - logf(ssum);
}

// ---------------- launch ----------------

extern "C" void kernel_launch(void* const* d_in, const int* in_sizes, int n_in,
                              void* d_out, int out_size, void* d_ws, size_t ws_size,
                              hipStream_t stream) {
    const float* x  = (const float*)d_in[0];
    const int*   ei = (const int*)d_in[1];
    const float* W1 = (const float*)d_in[2];
    const float* b1 = (const float*)d_in[3];
    const float* W2 = (const float*)d_in[4];
    const float* b2 = (const float*)d_in[5];
    float* out = (float*)d_out;

    const int n = in_sizes[0] / 512;     // 100000
    const int E = in_sizes[1] / 2;       // 3200000
    const int* src = ei;
    const int* dst = ei + E;

    // workspace layout (bytes), all 16B-aligned
    char* ws = (char*)d_ws;
    int*   deg     = (int*)(ws + 0);                   //   400,000
    int*   cursor  = (int*)(ws + 400000);              //   400,000
    float* dis     = (float*)(ws + 800000);            //   400,000
    int*   offsets = (int*)(ws + 1200000);             //   400,000
    int*   csr_src = (int*)(ws + 1600000);             //  12,800,000
    float* h1      = (float*)(ws + 14400000);          // 102,400,000 (reused as h2)
    float* out1    = (float*)(ws + 116800000);         // 102,400,000
    float* h2      = h1;

    // 1. CSR build
    k_init_deg<<<(n + TB - 1) / TB, TB, 0, stream>>>(deg, cursor, n);
    k_count_deg<<<(E + TB - 1) / TB, TB, 0, stream>>>(dst, E, deg);
    k_dis<<<(n + TB - 1) / TB, TB, 0, stream>>>(deg, dis, n);
    k_scan<<<1, 1024, 0, stream>>>(deg, offsets, n);
    k_fill<<<(E + TB - 1) / TB, TB, 0, stream>>>(src, dst, E, offsets, cursor, csr_src);

    // 2. h1 = x @ W1   [n,512]@[512,256]
    {
        dim3 grid((n + 63) / 64, 256 / 64);
        k_gemm<false><<<grid, TB, 0, stream>>>(x, W1, h1, n, 256, 512);
    }

    // 3. out1 = b1 + Â h1   (gather-side, no atomics)
    k_aggregate<256><<<(n + 3) / 4, TB, 0, stream>>>(h1, csr_src, offsets, deg, dis, b1, out1, n);

    // 4. h2 = relu(out1) @ W2   [n,256]@[256,64]
    {
        dim3 grid((n + 63) / 64, 64 / 64);
        k_gemm<true><<<grid, TB, 0, stream>>>(out1, W2, h2, n, 64, 256);
    }

    // 5. out = b2 + Â h2
    k_aggregate<64><<<(n + 3) / 4, TB, 0, stream>>>(h2, csr_src, offsets, deg, dis, b2, out, n);

    // 6. log_softmax rows of 64, in place
    k_logsoftmax64<<<(n * 64 + TB - 1) / TB, TB, 0, stream>>>(out, n);
}

// Round 4
// 941.935 us; speedup vs baseline: 12.7992x; 1.6267x over previous
//
#include <hip/hip_runtime.h>
#include <hip/hip_bf16.h>
#include <math.h>

#define TB 256

typedef __attribute__((ext_vector_type(8))) short bf16x8;
typedef __attribute__((ext_vector_type(4))) float f32x4;

__device__ inline float bf2f(ushort u) {
    union { uint u; float f; } c; c.u = ((uint)u) << 16; return c.f;
}
__device__ inline ushort f2bf(float f) {
    __hip_bfloat16 h = __float2bfloat16(f);
    union { __hip_bfloat16 h; ushort u; } c; c.h = h; return c.u;
}

// ---------------- casts ----------------

__global__ __launch_bounds__(256) void k_cast(const float* __restrict__ in,
                                              ushort* __restrict__ out, size_t n4) {
    size_t stride = (size_t)gridDim.x * blockDim.x;
    for (size_t i = blockIdx.x * (size_t)blockDim.x + threadIdx.x; i < n4; i += stride) {
        float4 v = ((const float4*)in)[i];
        ushort4 o;
        o.x = f2bf(v.x); o.y = f2bf(v.y); o.z = f2bf(v.z); o.w = f2bf(v.w);
        ((ushort4*)out)[i] = o;
    }
}

// WT[n][k] = bf16(W[k][n])
__global__ __launch_bounds__(256) void k_tcast(const float* __restrict__ W,
                                               ushort* __restrict__ WT, int K, int N) {
    int id = blockIdx.x * blockDim.x + threadIdx.x;
    if (id >= K * N) return;
    int k = id / N, nn = id % N;
    WT[(size_t)nn * K + k] = f2bf(W[id]);
}

// ---------------- degree / normalization ----------------

__global__ __launch_bounds__(256) void k_init_deg(int* deg, int* cursor, int n) {
    int i = blockIdx.x * blockDim.x + threadIdx.x;
    if (i < n) { deg[i] = 1; cursor[i] = 0; }
}

__global__ __launch_bounds__(256) void k_count_deg(const int* __restrict__ dst, int E, int* deg) {
    int i = blockIdx.x * blockDim.x + threadIdx.x;
    if (i < E) atomicAdd(&deg[dst[i]], 1);
}

__global__ __launch_bounds__(256) void k_dis(const int* __restrict__ deg, float* __restrict__ dis, int n) {
    int i = blockIdx.x * blockDim.x + threadIdx.x;
    if (i < n) dis[i] = rsqrtf((float)deg[i]);
}

// ---------------- exclusive scan of in-edge counts (deg-1), single block ----------------

__global__ __launch_bounds__(1024) void k_scan(const int* __restrict__ deg, int* __restrict__ offsets, int n) {
    __shared__ int sums[1024];
    int t = threadIdx.x;
    int C = (n + 1023) / 1024;
    int lo = t * C, hi = min(n, lo + C);
    int s = 0;
    for (int i = lo; i < hi; ++i) s += deg[i] - 1;
    sums[t] = s;
    __syncthreads();
    for (int off = 1; off < 1024; off <<= 1) {
        int v = (t >= off) ? sums[t - off] : 0;
        __syncthreads();
        sums[t] += v;
        __syncthreads();
    }
    int base = (t == 0) ? 0 : sums[t - 1];
    for (int i = lo; i < hi; ++i) { offsets[i] = base; base += deg[i] - 1; }
}

// ---------------- CSR fill (by dst) ----------------

__global__ __launch_bounds__(256) void k_fill(const int* __restrict__ src, const int* __restrict__ dst, int E,
                                              const int* __restrict__ offsets, int* cursor,
                                              int* __restrict__ csr_src) {
    int e = blockIdx.x * blockDim.x + threadIdx.x;
    if (e >= E) return;
    int d = dst[e];
    int pos = offsets[d] + atomicAdd(&cursor[d], 1);
    csr_src[pos] = src[e];
}

// ---------------- bf16 MFMA GEMM: C[M,N] = A[M,K] @ BT[N,K]^T, all bf16 ----------------
// BM=128, BN=64, BK=32; 4 waves (2x2); each wave 64x32 = 4x2 frags of 16x16.

__device__ inline uint relu_pk(uint u) {
    uint lo = u & 0x0000FFFFu;
    uint hi = u & 0xFFFF0000u;
    if (u & 0x00008000u) lo = 0;
    if (u & 0x80000000u) hi = 0;
    return lo | hi;
}

template <bool RELU>
__global__ __launch_bounds__(256) void k_gemm_mfma(const ushort* __restrict__ A,
                                                   const ushort* __restrict__ BT,
                                                   ushort* __restrict__ C,
                                                   int M, int N, int K) {
    const int BM = 128, BN = 64, BK = 32;
    __shared__ ushort Al[BM][40];   // pad to 40 (80 B rows) to spread banks
    __shared__ ushort Bl[BN][40];

    const int t    = threadIdx.x;
    const int lane = t & 63;
    const int wid  = t >> 6;
    const int wm   = wid >> 1, wn = wid & 1;
    const int m0   = blockIdx.x * BM, n0 = blockIdx.y * BN;
    const int lr   = lane & 15;     // row/col within fragment
    const int lg   = lane >> 4;     // k-group

    f32x4 acc[4][2] = {};

    for (int k0 = 0; k0 < K; k0 += BK) {
        // stage A: 128 rows x 32 bf16 = 512 chunks of 16B; 2 per thread
        #pragma unroll
        for (int i = 0; i < 2; ++i) {
            int c = t + i * 256;
            int row = c >> 2, q = c & 3;
            int gm = m0 + row;
            uint4 v = make_uint4(0, 0, 0, 0);
            if (gm < M) v = *(const uint4*)(A + (size_t)gm * K + k0 + q * 8);
            if (RELU) { v.x = relu_pk(v.x); v.y = relu_pk(v.y); v.z = relu_pk(v.z); v.w = relu_pk(v.w); }
            *(uint4*)(&Al[row][q * 8]) = v;
        }
        // stage B: 64 rows x 32 bf16 = 256 chunks; 1 per thread
        {
            int row = t >> 2, q = t & 3;
            uint4 v = *(const uint4*)(BT + (size_t)(n0 + row) * K + k0 + q * 8);
            *(uint4*)(&Bl[row][q * 8]) = v;
        }
        __syncthreads();

        bf16x8 fa[4], fb[2];
        #pragma unroll
        for (int mi = 0; mi < 4; ++mi)
            fa[mi] = *(const bf16x8*)(&Al[wm * 64 + mi * 16 + lr][lg * 8]);
        #pragma unroll
        for (int ni = 0; ni < 2; ++ni)
            fb[ni] = *(const bf16x8*)(&Bl[wn * 32 + ni * 16 + lr][lg * 8]);
        #pragma unroll
        for (int mi = 0; mi < 4; ++mi)
            #pragma unroll
            for (int ni = 0; ni < 2; ++ni)
                acc[mi][ni] = __builtin_amdgcn_mfma_f32_16x16x32_bf16(fa[mi], fb[ni], acc[mi][ni], 0, 0, 0);
        __syncthreads();
    }

    // epilogue: D row=(lg)*4+v, col=lr
    #pragma unroll
    for (int mi = 0; mi < 4; ++mi) {
        int rbase = m0 + wm * 64 + mi * 16 + lg * 4;
        #pragma unroll
        for (int v = 0; v < 4; ++v) {
            int gm = rbase + v;
            if (gm < M) {
                #pragma unroll
                for (int ni = 0; ni < 2; ++ni)
                    C[(size_t)gm * N + n0 + wn * 32 + ni * 16 + lr] = f2bf(acc[mi][ni][v]);
            }
        }
    }
}

// ---------------- gather aggregation (bf16 h), one wave per dst node ----------------

__global__ __launch_bounds__(256) void k_agg256(const ushort* __restrict__ h,
                                                const int* __restrict__ csr,
                                                const int* __restrict__ off,
                                                const int* __restrict__ deg,
                                                const float* __restrict__ dis,
                                                const float* __restrict__ bias,
                                                ushort* __restrict__ out, int n) {
    int wave = (int)((blockIdx.x * (size_t)blockDim.x + threadIdx.x) >> 6);
    int lane = threadIdx.x & 63;
    if (wave >= n) return;
    const int i = wave;
    const float di = dis[i];
    const int beg = off[i], cnt = deg[i] - 1, end = beg + cnt;

    float4 bv = ((const float4*)bias)[lane];
    ushort4 hv = ((const ushort4*)(h + (size_t)i * 256))[lane];
    float sl = di * di;
    float4 a0, a1 = make_float4(0.f, 0.f, 0.f, 0.f);
    a0.x = fmaf(bf2f(hv.x), sl, bv.x);
    a0.y = fmaf(bf2f(hv.y), sl, bv.y);
    a0.z = fmaf(bf2f(hv.z), sl, bv.z);
    a0.w = fmaf(bf2f(hv.w), sl, bv.w);

    for (int base = beg; base < end; base += 64) {
        int m = end - base; if (m > 64) m = 64;
        int   msrc = (lane < m) ? csr[base + lane] : 0;
        float mw   = (lane < m) ? dis[msrc] : 0.f;
        int k = 0;
        for (; k + 2 <= m; k += 2) {
            int   s0 = __shfl(msrc, k);     float w0 = __shfl(mw, k) * di;
            int   s1 = __shfl(msrc, k + 1); float w1 = __shfl(mw, k + 1) * di;
            ushort4 v0 = ((const ushort4*)(h + (size_t)s0 * 256))[lane];
            ushort4 v1 = ((const ushort4*)(h + (size_t)s1 * 256))[lane];
            a0.x = fmaf(bf2f(v0.x), w0, a0.x);
            a0.y = fmaf(bf2f(v0.y), w0, a0.y);
            a0.z = fmaf(bf2f(v0.z), w0, a0.z);
            a0.w = fmaf(bf2f(v0.w), w0, a0.w);
            a1.x = fmaf(bf2f(v1.x), w1, a1.x);
            a1.y = fmaf(bf2f(v1.y), w1, a1.y);
            a1.z = fmaf(bf2f(v1.z), w1, a1.z);
            a1.w = fmaf(bf2f(v1.w), w1, a1.w);
        }
        if (k < m) {
            int   s0 = __shfl(msrc, k); float w0 = __shfl(mw, k) * di;
            ushort4 v0 = ((const ushort4*)(h + (size_t)s0 * 256))[lane];
            a0.x = fmaf(bf2f(v0.x), w0, a0.x);
            a0.y = fmaf(bf2f(v0.y), w0, a0.y);
            a0.z = fmaf(bf2f(v0.z), w0, a0.z);
            a0.w = fmaf(bf2f(v0.w), w0, a0.w);
        }
    }
    ushort4 o;
    o.x = f2bf(a0.x + a1.x);
    o.y = f2bf(a0.y + a1.y);
    o.z = f2bf(a0.z + a1.z);
    o.w = f2bf(a0.w + a1.w);
    ((ushort4*)(out + (size_t)i * 256))[lane] = o;
}

__global__ __launch_bounds__(256) void k_agg64(const ushort* __restrict__ h,
                                               const int* __restrict__ csr,
                                               const int* __restrict__ off,
                                               const int* __restrict__ deg,
                                               const float* __restrict__ dis,
                                               const float* __restrict__ bias,
                                               float* __restrict__ out, int n) {
    int wave = (int)((blockIdx.x * (size_t)blockDim.x + threadIdx.x) >> 6);
    int lane = threadIdx.x & 63;
    if (wave >= n) return;
    const int i = wave;
    const float di = dis[i];
    const int beg = off[i], cnt = deg[i] - 1, end = beg + cnt;

    float a0 = fmaf(bf2f(h[(size_t)i * 64 + lane]), di * di, bias[lane]);
    float a1 = 0.f;

    for (int base = beg; base < end; base += 64) {
        int m = end - base; if (m > 64) m = 64;
        int   msrc = (lane < m) ? csr[base + lane] : 0;
        float mw   = (lane < m) ? dis[msrc] : 0.f;
        int k = 0;
        for (; k + 2 <= m; k += 2) {
            int   s0 = __shfl(msrc, k);     float w0 = __shfl(mw, k) * di;
            int   s1 = __shfl(msrc, k + 1); float w1 = __shfl(mw, k + 1) * di;
            a0 = fmaf(bf2f(h[(size_t)s0 * 64 + lane]), w0, a0);
            a1 = fmaf(bf2f(h[(size_t)s1 * 64 + lane]), w1, a1);
        }
        if (k < m) {
            int s0 = __shfl(msrc, k); float w0 = __shfl(mw, k) * di;
            a0 = fmaf(bf2f(h[(size_t)s0 * 64 + lane]), w0, a0);
        }
    }
    out[(size_t)i * 64 + lane] = a0 + a1;
}

// ---------------- log_softmax over rows of 64, in place ----------------

__global__ __launch_bounds__(256) void k_logsoftmax64(float* __restrict__ out, int n) {
    int wave = (int)((blockIdx.x * (size_t)blockDim.x + threadIdx.x) >> 6);
    int lane = threadIdx.x & 63;
    if (wave >= n) return;
    float v = out[(size_t)wave * 64 + lane];
    float m = v;
    #pragma unroll
    for (int o = 32; o > 0; o >>= 1) m = fmaxf(m, __shfl_xor(m, o));
    float ex = __expf(v - m);
    float ssum = ex;
    #pragma unroll
    for (int o = 32; o > 0; o >>= 1) ssum += __shfl_xor(ssum, o);
    out[(size_t)wave * 64 + lane] = v - m - logf(ssum);
}

// ---------------- launch ----------------

extern "C" void kernel_launch(void* const* d_in, const int* in_sizes, int n_in,
                              void* d_out, int out_size, void* d_ws, size_t ws_size,
                              hipStream_t stream) {
    const float* x  = (const float*)d_in[0];
    const int*   ei = (const int*)d_in[1];
    const float* W1 = (const float*)d_in[2];
    const float* b1 = (const float*)d_in[3];
    const float* W2 = (const float*)d_in[4];
    const float* b2 = (const float*)d_in[5];
    float* out = (float*)d_out;

    const int n = in_sizes[0] / 512;     // 100000
    const int E = in_sizes[1] / 2;       // 3200000
    const int* src = ei;
    const int* dst = ei + E;

    // workspace layout (bytes), 16B-aligned blocks
    char* ws = (char*)d_ws;
    int*    deg     = (int*)(ws + 0);                  //    400,000
    int*    cursor  = (int*)(ws + 400000);             //    400,000
    float*  dis     = (float*)(ws + 800000);           //    400,000
    int*    offsets = (int*)(ws + 1200000);            //    400,000
    int*    csr_src = (int*)(ws + 1600000);            // 12,800,000 -> ends 14,400,000
    ushort* x_bf    = (ushort*)(ws + 14400000);        // 102,400,000 -> ends 116,800,000 (dead after GEMM1)
    ushort* out1    = (ushort*)(ws + 14400000);        // 51,200,000 (aliases x_bf, written after GEMM1 done)
    ushort* h2      = (ushort*)(ws + 65600000);        // 12,800,000 -> ends 78,400,000
    ushort* W1T     = (ushort*)(ws + 116800000);       //    262,144 -> ends 117,062,144
    ushort* W2T     = (ushort*)(ws + 117062144);       //     32,768 -> ends 117,094,912
    ushort* h1      = (ushort*)(ws + 117094912);       // 51,200,000 -> ends 168,294,912

    // 0. casts / pre-transposes
    k_cast<<<2048, TB, 0, stream>>>(x, x_bf, (size_t)n * 128);
    k_tcast<<<(512 * 256 + TB - 1) / TB, TB, 0, stream>>>(W1, W1T, 512, 256);
    k_tcast<<<(256 * 64 + TB - 1) / TB, TB, 0, stream>>>(W2, W2T, 256, 64);

    // 1. CSR build
    k_init_deg<<<(n + TB - 1) / TB, TB, 0, stream>>>(deg, cursor, n);
    k_count_deg<<<(E + TB - 1) / TB, TB, 0, stream>>>(dst, E, deg);
    k_dis<<<(n + TB - 1) / TB, TB, 0, stream>>>(deg, dis, n);
    k_scan<<<1, 1024, 0, stream>>>(deg, offsets, n);
    k_fill<<<(E + TB - 1) / TB, TB, 0, stream>>>(src, dst, E, offsets, cursor, csr_src);

    // 2. h1 = x @ W1  (bf16 MFMA)
    {
        dim3 grid((n + 127) / 128, 256 / 64);
        k_gemm_mfma<false><<<grid, TB, 0, stream>>>(x_bf, W1T, h1, n, 256, 512);
    }

    // 3. out1 = b1 + Â h1
    k_agg256<<<(n + 3) / 4, TB, 0, stream>>>(h1, csr_src, offsets, deg, dis, b1, out1, n);

    // 4. h2 = relu(out1) @ W2  (bf16 MFMA, relu fused into A staging)
    {
        dim3 grid((n + 127) / 128, 1);
        k_gemm_mfma<true><<<grid, TB, 0, stream>>>(out1, W2T, h2, n, 64, 256);
    }

    // 5. out = b2 + Â h2  (fp32 into d_out)
    k_agg64<<<(n + 3) / 4, TB, 0, stream>>>(h2, csr_src, offsets, deg, dis, b2, out, n);

    // 6. log_softmax rows of 64, in place
    k_logsoftmax64<<<(n * 64 + TB - 1) / TB, TB, 0, stream>>>(out, n);
}